// Round 16
// baseline (179.908 us; speedup 1.0000x reference)
//
#include <hip/hip_runtime.h>

typedef float f32x4  __attribute__((ext_vector_type(4)));
typedef __bf16 bf16x8 __attribute__((ext_vector_type(8)));

#define SPAT 65536   // t*h*w
#define CH   128
#define NE   8

// LDS (per 256-thread block): 38,944 B -> 3-4 blocks/CU
#define SLOT_OFF 0       // 32768 : W1[e] bf16 image (single-buffered)
#define B1_OFF   32768   // 4096  : b1 f32[8][128]
#define B2T_OFF  36864   // 2048  : b2^T bf16[128][8]
#define AL_OFF   38912   // 32    : alpha f32[8]
#define LDS_BYTES 38944

static __device__ __forceinline__ unsigned short bf(float f) {
    __bf16 h = (__bf16)f; return __builtin_bit_cast(unsigned short, h);
}
static __device__ __forceinline__ unsigned pk2(float a, float b) {
    return (unsigned)bf(a) | ((unsigned)bf(b) << 16);
}

typedef const __attribute__((address_space(1))) void* as1cp;
typedef __attribute__((address_space(3))) void* as3p;
static __device__ __forceinline__ void gload16(const void* g, void* l) {
    __builtin_amdgcn_global_load_lds((as1cp)g, (as3p)l, 16, 0, 0);
}

// Pre-convert W1/W2 fp32 -> bf16 LINE images for 16x16x32 MFMA.
// A/B frag (blocked-k, analog of R7-verified 32x32 layout): lane l holds
//   row/col = l&15, k = (l>>4)*8 + j  (8 bf16 = 16B per lane; 1KB per line).
// W1 image: line L = g*4 + b (g = 16-row o-group, b = 32-chan k-block).
//   Lane slot (L, l): image row r_t = l&15 within group g, channels
//   c = 32b + 8*(l>>4) + j. Rows PERMUTED so GEMM1's D-frag == GEMM2's A-frag:
//   real W1 row = 32*(g>>1) + 8*(r_t>>2) + 4*(g&1) + (r_t&3).
// W2 image: line L = b*8 + pt; lane: p = pt*16 + (l&15), c = 32b + 8*(l>>4) + j.
__global__ void conv_w(const float* __restrict__ W1, const float* __restrict__ W2,
                       unsigned char* __restrict__ wimg) {
    const int gid = blockIdx.x * 256 + threadIdx.x;   // 32768 lane-slots
    const int mat = gid >> 14;
    const int e   = (gid >> 11) & 7;
    const int L   = (gid >> 6) & 31;
    const int l   = gid & 63;
    const int qk  = l >> 4;
    const float* s;
    if (mat == 0) {
        const int g = L >> 2, b = L & 3, rt = l & 15;
        const int P = ((g >> 1) << 5) + ((rt >> 2) << 3) + ((g & 1) << 2) + (rt & 3);
        s = W1 + e * 16384 + P * 128 + (b << 5) + (qk << 3);
    } else {
        const int bb = L >> 3, pt = L & 7;
        const int p = (pt << 4) + (l & 15);
        s = W2 + e * 16384 + p * 128 + (bb << 5) + (qk << 3);
    }
    uint4 pk;
    pk.x = pk2(s[0], s[1]); pk.y = pk2(s[2], s[3]);
    pk.z = pk2(s[4], s[5]); pk.w = pk2(s[6], s[7]);
    *(uint4*)(wimg + mat * 262144 + e * 32768 + L * 1024 + l * 16) = pk;
}

// stage one 32KB W1 image into the LDS slot (8 x gload16 per thread, 256 thr)
static __device__ __forceinline__ void stage_w(const unsigned char* __restrict__ src,
                                               unsigned char* dst, int t) {
    const int off = t * 16;
    #pragma unroll
    for (int k = 0; k < 8; ++k)
        gload16(src + k * 4096 + off, dst + k * 4096 + off);
}

// 256-thr (4-wave) blocks; 16 tokens/wave. Small reg set (~120 incl acc 32)
// -> waves_per_eu(3,8): 3+ waves/SIMD, 3 blocks/CU co-resident; blocks
// free-run so one block's barrier/DMA drain is covered by the others.
__global__ __launch_bounds__(256) __attribute__((amdgpu_waves_per_eu(3, 8)))
void moe_main(const float* __restrict__ x,  const float* __restrict__ gw,
              const float* __restrict__ gb, const float* __restrict__ b1,
              const float* __restrict__ alpha, const float* __restrict__ b2,
              const unsigned char* __restrict__ wimg, float* __restrict__ out)
{
    __shared__ __align__(16) unsigned char smem[LDS_BYTES];
    const int t = threadIdx.x, l = t & 63, wv = t >> 6, blk = blockIdx.x;
    const int tk = l & 15, q = l >> 4;
    const size_t xbase = (size_t)(blk >> 10) * (size_t)(CH * SPAT) + (size_t)((blk & 1023) << 6);
    const int m = wv * 16 + tk;      // this lane's block-local token (0..63)
    const int wl16 = l * 16;         // lane byte offset within any 1KB line

    // W1[0] -> slot: issue at entry, drained by S1
    stage_w(wimg, smem + SLOT_OFF, t);

    // stage small params
    if (t < 256) ((f32x4*)(smem + B1_OFF))[t] = ((const f32x4*)b1)[t];
    if (t < 128) {
        uint4 p;
        p.x = pk2(b2[0 * 128 + t], b2[1 * 128 + t]);
        p.y = pk2(b2[2 * 128 + t], b2[3 * 128 + t]);
        p.z = pk2(b2[4 * 128 + t], b2[5 * 128 + t]);
        p.w = pk2(b2[6 * 128 + t], b2[7 * 128 + t]);
        *(uint4*)(smem + B2T_OFF + t * 16) = p;
    } else if (t >= 128 && t < 136) {
        ((float*)(smem + AL_OFF))[t - 128] = alpha[t - 128];
    }

    // ---- x load (32 ch/lane), fp32 gating partials, xb pack ----
    f32x4 plo = {0.f,0.f,0.f,0.f}, phi = {0.f,0.f,0.f,0.f};
    uint4 xb[4];
    #pragma unroll
    for (int b = 0; b < 4; ++b) {
        const int c0 = b * 32 + q * 8;
        float v8[8];
        #pragma unroll
        for (int j = 0; j < 8; ++j) v8[j] = x[xbase + (size_t)(c0 + j) * SPAT + m];
        #pragma unroll
        for (int j = 0; j < 8; ++j) {
            const f32x4 g0 = *(const f32x4*)(gw + (c0 + j) * NE);
            const f32x4 g1 = *(const f32x4*)(gw + (c0 + j) * NE + 4);
            plo += v8[j] * g0; phi += v8[j] * g1;
        }
        xb[b].x = pk2(v8[0], v8[1]); xb[b].y = pk2(v8[2], v8[3]);
        xb[b].z = pk2(v8[4], v8[5]); xb[b].w = pk2(v8[6], v8[7]);
    }
    // reduce partials across the 4 q-groups (lanes l, l^16, l^32, l^48)
    #pragma unroll
    for (int i2 = 0; i2 < 4; ++i2) {
        plo[i2] += __shfl_xor(plo[i2], 16, 64);
        phi[i2] += __shfl_xor(phi[i2], 16, 64);
        plo[i2] += __shfl_xor(plo[i2], 32, 64);
        phi[i2] += __shfl_xor(phi[i2], 32, 64);
    }
    int i0, i1; float q0, q1; uint4 cbw;
    {
        float lg[8];
        #pragma unroll
        for (int e2 = 0; e2 < 4; ++e2) { lg[e2] = plo[e2] + gb[e2]; lg[4 + e2] = phi[e2] + gb[4 + e2]; }
        i0 = 0; float v0 = lg[0];
        #pragma unroll
        for (int e2 = 1; e2 < 8; ++e2) if (lg[e2] > v0) { v0 = lg[e2]; i0 = e2; }
        i1 = -1; float v1 = -3.4e38f;
        #pragma unroll
        for (int e2 = 0; e2 < 8; ++e2) if (e2 != i0 && lg[e2] > v1) { v1 = lg[e2]; i1 = e2; }
        const float d = expf(v1 - v0);
        q0 = 1.f / (1.f + d);
        q1 = d   / (1.f + d);
        float cb[8];
        #pragma unroll
        for (int e2 = 0; e2 < 8; ++e2) cb[e2] = (e2 == i0) ? q0 : ((e2 == i1) ? q1 : 0.f);
        cbw.x = pk2(cb[0], cb[1]); cbw.y = pk2(cb[2], cb[3]);
        cbw.z = pk2(cb[4], cb[5]); cbw.w = pk2(cb[6], cb[7]);
    }
    __syncthreads();   // S1: W1[0] landed, params visible

    f32x4 acc[8] = {};   // acc[pt]: D2[tok = wv*16 + 4q + i][p = pt*16 + tk]

    #pragma unroll 1
    for (int e = 0; e < NE; ++e) {
        const float alph = ((const float*)(smem + AL_OFF))[e];
        const float ce = (i0 == e) ? q0 : ((i1 == e) ? q1 : 0.f);

        // ---- GEMM1: h1[all 128 o][lane's token tk] -> pa registers ----
        uint4 pa[4];
        #pragma unroll 2
        for (int g = 0; g < 8; ++g) {
            uint4 a1[4];
            #pragma unroll
            for (int b = 0; b < 4; ++b)
                a1[b] = *(const uint4*)(smem + SLOT_OFF + (g * 4 + b) * 1024 + wl16);
            f32x4 h = {0.f, 0.f, 0.f, 0.f};
            #pragma unroll
            for (int b = 0; b < 4; ++b)
                h = __builtin_amdgcn_mfma_f32_16x16x32_bf16(
                        __builtin_bit_cast(bf16x8, a1[b]),
                        __builtin_bit_cast(bf16x8, xb[b]), h, 0, 0, 0);
            // lane's D1 rows: real o = 32*(g>>1) + 8q + 4*(g&1) + i
            const int ob = ((g >> 1) << 5) + (q << 3) + ((g & 1) << 2);
            const f32x4 b1v = *(const f32x4*)(smem + B1_OFF + e * 512 + ob * 4);
            float hv[4];
            #pragma unroll
            for (int i = 0; i < 4; ++i) {
                float z = h[i] + b1v[i];
                z = (z > 0.f) ? z : alph * z;
                hv[i] = z * ce;
            }
            // A-frag slot for GEMM2: k-block g>>1, j = 4*(g&1)+i
            ((unsigned*)&pa[g >> 1])[(g & 1) * 2]     = pk2(hv[0], hv[1]);
            ((unsigned*)&pa[g >> 1])[(g & 1) * 2 + 1] = pk2(hv[2], hv[3]);
        }
        __syncthreads();                       // all waves done reading slot
        if (e < 7) stage_w(wimg + (e + 1) * 32768, smem + SLOT_OFF, t);

        // ---- GEMM2: acc[tok][p] += h1(regs) . W2 (global, L1-resident) ----
        const unsigned char* W2g = wimg + 262144 + e * 32768;
        #pragma unroll 2
        for (int b = 0; b < 4; ++b) {
            #pragma unroll
            for (int pt = 0; pt < 8; ++pt) {
                const uint4 wf = *(const uint4*)(W2g + (b * 8 + pt) * 1024 + wl16);
                acc[pt] = __builtin_amdgcn_mfma_f32_16x16x32_bf16(
                        __builtin_bit_cast(bf16x8, pa[b]),
                        __builtin_bit_cast(bf16x8, wf), acc[pt], 0, 0, 0);
            }
        }
        if (e < 7) __syncthreads();            // drains W1[e+1] DMA (vmcnt0)
    }

    // ---- bias-combine as one K=32 MFMA per p-tile: acc += combine . b2 ----
    {
        const uint4 z4 = {0u, 0u, 0u, 0u};
        const uint4 aop = (q == 0) ? cbw : z4;   // A[row=tk][k=e], k=8q+j
        #pragma unroll
        for (int pt = 0; pt < 8; ++pt) {
            const uint4 bop = (q == 0)
                ? *(const uint4*)(smem + B2T_OFF + (pt * 16 + tk) * 16) : z4;
            acc[pt] = __builtin_amdgcn_mfma_f32_16x16x32_bf16(
                    __builtin_bit_cast(bf16x8, aop),
                    __builtin_bit_cast(bf16x8, bop), acc[pt], 0, 0, 0);
        }
    }

    // ---- epilogue: residual + f32x4 stores (tokens wv*16 + 4q + 0..3) ----
    #pragma unroll
    for (int pt = 0; pt < 8; ++pt) {
        const int p = pt * 16 + tk;
        const size_t a = xbase + (size_t)p * SPAT + (wv * 16 + q * 4);
        const f32x4 xv = *(const f32x4*)(x + a);
        f32x4 r;
        #pragma unroll
        for (int i = 0; i < 4; ++i) r[i] = acc[pt][i] + xv[i];
        *(f32x4*)(out + a) = r;
    }
}

extern "C" void kernel_launch(void* const* d_in, const int* in_sizes, int n_in,
                              void* d_out, int out_size, void* d_ws, size_t ws_size,
                              hipStream_t stream) {
    const float* x  = (const float*)d_in[0];
    const float* gw = (const float*)d_in[1];
    const float* gb = (const float*)d_in[2];
    const float* W1 = (const float*)d_in[3];
    const float* b1 = (const float*)d_in[4];
    const float* al = (const float*)d_in[5];
    const float* W2 = (const float*)d_in[6];
    const float* b2 = (const float*)d_in[7];
    (void)in_sizes; (void)n_in; (void)out_size; (void)ws_size;
    unsigned char* wimg = (unsigned char*)d_ws;   // needs 512 KiB
    float* out = (float*)d_out;

    conv_w<<<dim3(128), dim3(256), 0, stream>>>(W1, W2, wimg);
    moe_main<<<dim3(2048), dim3(256), 0, stream>>>(x, gw, gb, b1, al, b2, wimg, out);
}